// Round 6
// baseline (182.524 us; speedup 1.0000x reference)
//
#include <hip/hip_runtime.h>
#include <math.h>

// Round 6: everything matmul-shaped on MFMA.
// k_qkv: theta/phi/origin convs via bf16 MFMA (hi/lo 3-term for score path),
//        Q[pix][hi|lo] interleaved, K pooled -> [pos][hi|lo], V -> [32][1024].
//        log2(e) folded into theta weights/bias -> attention uses exp2.
// k_attn: Q preloaded frags; K half-chunk ping-pong register prefetch; V
//        prefetched a phase ahead; no barriers in main loop; W-conv epilogue
//        on MFMA (y hi/lo through LDS).

#define B_SZ 16
#define C_IN 64
#define C_INT 32
#define HW 4096
#define NKV 1024
#define CHK 128
#define NCHUNK 8
#define PSTR 136   // P row stride (ushorts): 128 kv + 8 pad
#define YSTR 40    // sY row stride (ushorts): 32 ch + 8 pad
#define LOG2E 1.4426950408889634f

typedef __attribute__((ext_vector_type(8))) short bfrag;
typedef __attribute__((ext_vector_type(4))) float f32x4;

static __device__ __forceinline__ ushort f2bf(float v) {
  union { float f; uint u; } c; c.f = v;
  uint b = c.u + 0x7FFFu + ((c.u >> 16) & 1u);
  return (ushort)(b >> 16);
}
static __device__ __forceinline__ float bf2f(ushort h) {
  union { uint u; float f; } c; c.u = (uint)h << 16; return c.f;
}

// ---------------- kernel 1: Q/K/V via MFMA ----------------
// 1024 thr = 16 waves; block = 256 pixels = 4 image rows; grid = 16*16.
// Wave W: row = W>>2, m-tile = W&3 (16 pixels). A = x[m=pix][k=ch] (hi/lo),
// B = w^T[k=ch][n=out] (hi/lo). D: row(quad*4+r)=pix, col(l15)=outch.
__global__ __launch_bounds__(1024, 4) void k_qkv(
    const float* __restrict__ x,
    const float* __restrict__ wt, const float* __restrict__ bt,
    const float* __restrict__ wp, const float* __restrict__ bp,
    const float* __restrict__ wo, const float* __restrict__ bo,
    ushort* __restrict__ Qi, ushort* __restrict__ Ki, ushort* __restrict__ Vt) {
  __shared__ float sPool[2][4][32][33];   // [conv][row][pooled x][ch]

  int t = threadIdx.x;
  int W = t >> 6, lane = t & 63, l15 = lane & 15, quad = lane >> 4;
  int row = W >> 2, mt = W & 3;
  int bb = blockIdx.x >> 4, rb = blockIdx.x & 15;
  int p0 = rb * 256;
  int pixm = p0 + row * 64 + mt * 16;     // m-tile base pixel

  // ---- x A-frags, hi/lo, two k-halves (strided global loads, 4x64B/inst)
  bfrag xh[2], xl[2];
  const float* xbase = x + ((size_t)bb << 18) + pixm + l15;
  #pragma unroll
  for (int kh = 0; kh < 2; ++kh)
    #pragma unroll
    for (int j = 0; j < 8; ++j) {
      float v = xbase[(size_t)(kh * 32 + quad * 8 + j) << 12];
      ushort hb = f2bf(v);
      xh[kh][j] = (short)hb;
      xl[kh][j] = (short)f2bf(v - bf2f(hb));
    }

  f32x4 acc[2];

  // ---- THETA (scaled by LOG2E), 3-term hi/lo -> Q interleaved
  acc[0] = (f32x4){0.f,0.f,0.f,0.f}; acc[1] = (f32x4){0.f,0.f,0.f,0.f};
  #pragma unroll
  for (int kh = 0; kh < 2; ++kh)
    #pragma unroll
    for (int nt = 0; nt < 2; ++nt) {
      bfrag wh, wl;
      const float* wrow = wt + (size_t)(nt * 16 + l15) * 64 + kh * 32 + quad * 8;
      #pragma unroll
      for (int j = 0; j < 8; ++j) {
        float v = wrow[j] * LOG2E;
        ushort hb = f2bf(v);
        wh[j] = (short)hb; wl[j] = (short)f2bf(v - bf2f(hb));
      }
      acc[nt] = __builtin_amdgcn_mfma_f32_16x16x32_bf16(xh[kh], wh, acc[nt], 0, 0, 0);
      acc[nt] = __builtin_amdgcn_mfma_f32_16x16x32_bf16(xl[kh], wh, acc[nt], 0, 0, 0);
      acc[nt] = __builtin_amdgcn_mfma_f32_16x16x32_bf16(xh[kh], wl, acc[nt], 0, 0, 0);
    }
  #pragma unroll
  for (int nt = 0; nt < 2; ++nt) {
    float bias = bt[nt * 16 + l15] * LOG2E;
    ushort* qb = Qi + ((size_t)bb * HW + pixm) * 64 + nt * 16 + l15;
    #pragma unroll
    for (int r = 0; r < 4; ++r) {
      float v = acc[nt][r] + bias;
      ushort hb = f2bf(v);
      qb[(size_t)(quad * 4 + r) * 64]      = hb;
      qb[(size_t)(quad * 4 + r) * 64 + 32] = f2bf(v - bf2f(hb));
    }
  }

  // ---- PHI, 3-term hi/lo -> x-pair max partials in LDS
  acc[0] = (f32x4){0.f,0.f,0.f,0.f}; acc[1] = (f32x4){0.f,0.f,0.f,0.f};
  #pragma unroll
  for (int kh = 0; kh < 2; ++kh)
    #pragma unroll
    for (int nt = 0; nt < 2; ++nt) {
      bfrag wh, wl;
      const float* wrow = wp + (size_t)(nt * 16 + l15) * 64 + kh * 32 + quad * 8;
      #pragma unroll
      for (int j = 0; j < 8; ++j) {
        float v = wrow[j];
        ushort hb = f2bf(v);
        wh[j] = (short)hb; wl[j] = (short)f2bf(v - bf2f(hb));
      }
      acc[nt] = __builtin_amdgcn_mfma_f32_16x16x32_bf16(xh[kh], wh, acc[nt], 0, 0, 0);
      acc[nt] = __builtin_amdgcn_mfma_f32_16x16x32_bf16(xl[kh], wh, acc[nt], 0, 0, 0);
      acc[nt] = __builtin_amdgcn_mfma_f32_16x16x32_bf16(xh[kh], wl, acc[nt], 0, 0, 0);
    }
  {
    int px = mt * 8 + quad * 2;
    #pragma unroll
    for (int nt = 0; nt < 2; ++nt) {
      float bias = bp[nt * 16 + l15];
      sPool[0][row][px    ][nt * 16 + l15] = fmaxf(acc[nt][0], acc[nt][1]) + bias;
      sPool[0][row][px + 1][nt * 16 + l15] = fmaxf(acc[nt][2], acc[nt][3]) + bias;
    }
  }

  // ---- ORIGIN (V), 1-term (bf16-rounded at store anyway)
  acc[0] = (f32x4){0.f,0.f,0.f,0.f}; acc[1] = (f32x4){0.f,0.f,0.f,0.f};
  #pragma unroll
  for (int kh = 0; kh < 2; ++kh)
    #pragma unroll
    for (int nt = 0; nt < 2; ++nt) {
      bfrag wh;
      const float* wrow = wo + (size_t)(nt * 16 + l15) * 64 + kh * 32 + quad * 8;
      #pragma unroll
      for (int j = 0; j < 8; ++j) wh[j] = (short)f2bf(wrow[j]);
      acc[nt] = __builtin_amdgcn_mfma_f32_16x16x32_bf16(xh[kh], wh, acc[nt], 0, 0, 0);
      acc[nt] = __builtin_amdgcn_mfma_f32_16x16x32_bf16(xl[kh], wh, acc[nt], 0, 0, 0);
    }
  {
    int px = mt * 8 + quad * 2;
    #pragma unroll
    for (int nt = 0; nt < 2; ++nt) {
      float bias = bo[nt * 16 + l15];
      sPool[1][row][px    ][nt * 16 + l15] = fmaxf(acc[nt][0], acc[nt][1]) + bias;
      sPool[1][row][px + 1][nt * 16 + l15] = fmaxf(acc[nt][2], acc[nt][3]) + bias;
    }
  }
  __syncthreads();

  // ---- final pooling across row pairs -> K (hi/lo) and V (transposed)
  for (int f = t; f < 2048; f += 1024) {
    int pr = f >> 10, rem = f & 1023;
    int px = rem >> 5, ch = rem & 31;
    size_t pos = (size_t)(rb * 2 + pr) * 32 + px;
    float kv = fmaxf(sPool[0][2*pr][px][ch], sPool[0][2*pr+1][px][ch]);
    ushort hb = f2bf(kv);
    ushort* kb = Ki + ((size_t)bb * NKV + pos) * 64 + ch;
    kb[0]  = hb;
    kb[32] = f2bf(kv - bf2f(hb));
    float vv = fmaxf(sPool[1][2*pr][px][ch], sPool[1][2*pr+1][px][ch]);
    Vt[(size_t)bb * 32 * NKV + (size_t)ch * NKV + pos] = f2bf(vv);
  }
}

// ---------------- kernel 2: MFMA flash attention + MFMA W-conv ----------------
// 256 thr = 4 waves x 16 q-rows; block = 64 rows; grid = 16*64.
__global__ __launch_bounds__(256, 3) void k_attn(
    const ushort* __restrict__ Qi, const ushort* __restrict__ Ki,
    const ushort* __restrict__ Vt,
    const float* __restrict__ x, const float* __restrict__ wW,
    const float* __restrict__ bW, float* __restrict__ z) {
  __shared__ __align__(16) ushort sPQ[4 * 16 * PSTR];   // 17408 B (P; reused as sY)

  int t = threadIdx.x;
  int wave = t >> 6, lane = t & 63, l15 = lane & 15, quad = lane >> 4;
  int bb = blockIdx.x >> 6;
  int p0 = (blockIdx.x & 63) << 6;
  int q0 = p0 + wave * 16;

  // ---- Q frags (B[k=ch quad*8+j][n=qrow l15]), interleaved hi|lo
  const ushort* qrow = Qi + ((size_t)bb * HW + q0 + l15) * 64 + quad * 8;
  bfrag qh = *(const bfrag*)qrow;
  bfrag ql = *(const bfrag*)(qrow + 32);

  const ushort* Kb = Ki + (size_t)bb * NKV * 64;
  const ushort* Vb = Vt + (size_t)bb * 32 * NKV;
  ushort* myP = sPQ + wave * 16 * PSTR;

  bfrag khA[4], klA[4], khB[4], klB[4], vb[8];
  auto loadK = [&](bfrag* kh, bfrag* kl, int c, int h) {
    #pragma unroll
    for (int tt = 0; tt < 4; ++tt) {
      const ushort* p = Kb + (size_t)(c * CHK + h * 64 + tt * 16 + l15) * 64 + quad * 8;
      kh[tt] = *(const bfrag*)p;
      kl[tt] = *(const bfrag*)(p + 32);
    }
  };
  auto loadV = [&](int c) {
    #pragma unroll
    for (int ks = 0; ks < 4; ++ks) {
      vb[2*ks+0] = *(const bfrag*)(Vb + (size_t)l15 * NKV        + c * CHK + ks * 32 + quad * 8);
      vb[2*ks+1] = *(const bfrag*)(Vb + (size_t)(16 + l15) * NKV + c * CHK + ks * 32 + quad * 8);
    }
  };

  f32x4 accO[2], accS;
  accO[0] = (f32x4){0.f,0.f,0.f,0.f};
  accO[1] = (f32x4){0.f,0.f,0.f,0.f};
  accS    = (f32x4){0.f,0.f,0.f,0.f};
  bfrag vones;
  #pragma unroll
  for (int i = 0; i < 8; ++i) vones[i] = (short)0x3F80;

  auto procS = [&](bfrag kh, bfrag kl, int tt) {
    f32x4 s = (f32x4){0.f,0.f,0.f,0.f};
    s = __builtin_amdgcn_mfma_f32_16x16x32_bf16(kh, qh, s, 0, 0, 0);
    s = __builtin_amdgcn_mfma_f32_16x16x32_bf16(kh, ql, s, 0, 0, 0);
    s = __builtin_amdgcn_mfma_f32_16x16x32_bf16(kl, qh, s, 0, 0, 0);
    float e0 = exp2f(s[0]), e1 = exp2f(s[1]);
    float e2 = exp2f(s[2]), e3 = exp2f(s[3]);
    uint2 pk;
    pk.x = (__float_as_uint(e0) >> 16) | (__float_as_uint(e1) & 0xFFFF0000u);
    pk.y = (__float_as_uint(e2) >> 16) | (__float_as_uint(e3) & 0xFFFF0000u);
    *(uint2*)&myP[l15 * PSTR + tt * 16 + quad * 4] = pk;
  };

  loadK(khA, klA, 0, 0);
  loadK(khB, klB, 0, 1);
  loadV(0);

  for (int c = 0; c < NCHUNK; ++c) {
    #pragma unroll
    for (int tt = 0; tt < 4; ++tt) procS(khA[tt], klA[tt], tt);
    if (c + 1 < NCHUNK) loadK(khA, klA, c + 1, 0);     // prefetch next half-chunk
    #pragma unroll
    for (int tt = 0; tt < 4; ++tt) procS(khB[tt], klB[tt], 4 + tt);
    if (c + 1 < NCHUNK) loadK(khB, klB, c + 1, 1);

    #pragma unroll
    for (int ks = 0; ks < 4; ++ks) {
      bfrag a = *(const bfrag*)&myP[l15 * PSTR + ks * 32 + quad * 8];
      accO[0] = __builtin_amdgcn_mfma_f32_16x16x32_bf16(a, vb[2*ks],   accO[0], 0, 0, 0);
      accO[1] = __builtin_amdgcn_mfma_f32_16x16x32_bf16(a, vb[2*ks+1], accO[1], 0, 0, 0);
      accS    = __builtin_amdgcn_mfma_f32_16x16x32_bf16(a, vones,      accS,    0, 0, 0);
    }
    if (c + 1 < NCHUNK) loadV(c + 1);                  // V a full phase early
  }

  // ---- normalize -> y (bf16 hi/lo) into LDS
  __syncthreads();            // P buffers dead everywhere
  ushort* sYh = sPQ;
  ushort* sYl = sPQ + 64 * YSTR;
  #pragma unroll
  for (int r = 0; r < 4; ++r) {
    float inv = __builtin_amdgcn_rcpf(accS[r]);
    int rr = (wave * 16 + quad * 4 + r) * YSTR;
    float y0 = accO[0][r] * inv, y1 = accO[1][r] * inv;
    ushort h0 = f2bf(y0), h1 = f2bf(y1);
    sYh[rr + l15]      = h0;  sYl[rr + l15]      = f2bf(y0 - bf2f(h0));
    sYh[rr + 16 + l15] = h1;  sYl[rr + 16 + l15] = f2bf(y1 - bf2f(h1));
  }

  // ---- W-conv A-frags: wave owns out-ch tile [wave*16, wave*16+16)
  bfrag ah, al;
  {
    const float* wrow = wW + (size_t)(wave * 16 + l15) * 32 + quad * 8;
    #pragma unroll
    for (int j = 0; j < 8; ++j) {
      float v = wrow[j];
      ushort hb = f2bf(v);
      ah[j] = (short)hb; al[j] = (short)f2bf(v - bf2f(hb));
    }
  }
  float bWr[4];
  #pragma unroll
  for (int r = 0; r < 4; ++r) bWr[r] = bW[wave * 16 + quad * 4 + r];
  __syncthreads();            // sY fully written

  // ---- z = W.y + bW + x  (D: row=outch quad*4+r, col=pix l15)
  #pragma unroll
  for (int nt = 0; nt < 4; ++nt) {
    bfrag yh = *(const bfrag*)&sYh[(nt * 16 + l15) * YSTR + quad * 8];
    bfrag yl = *(const bfrag*)&sYl[(nt * 16 + l15) * YSTR + quad * 8];
    f32x4 d = (f32x4){0.f,0.f,0.f,0.f};
    d = __builtin_amdgcn_mfma_f32_16x16x32_bf16(ah, yh, d, 0, 0, 0);
    d = __builtin_amdgcn_mfma_f32_16x16x32_bf16(al, yh, d, 0, 0, 0);
    d = __builtin_amdgcn_mfma_f32_16x16x32_bf16(ah, yl, d, 0, 0, 0);
    #pragma unroll
    for (int r = 0; r < 4; ++r) {
      size_t zi = ((size_t)bb << 18) + ((size_t)(wave * 16 + quad * 4 + r) << 12)
                + p0 + nt * 16 + l15;
      z[zi] = d[r] + bWr[r] + x[zi];
    }
  }
}

extern "C" void kernel_launch(void* const* d_in, const int* in_sizes, int n_in,
                              void* d_out, int out_size, void* d_ws, size_t ws_size,
                              hipStream_t stream) {
  const float* x   = (const float*)d_in[0];
  const float* w_o = (const float*)d_in[1];
  const float* b_o = (const float*)d_in[2];
  const float* w_t = (const float*)d_in[3];
  const float* b_t = (const float*)d_in[4];
  const float* w_p = (const float*)d_in[5];
  const float* b_p = (const float*)d_in[6];
  const float* w_W = (const float*)d_in[7];
  const float* b_W = (const float*)d_in[8];
  float* z = (float*)d_out;

  ushort* Qi = (ushort*)d_ws;                               // 16*4096*64
  ushort* Ki = Qi + (size_t)B_SZ * HW * 64;                 // 16*1024*64
  ushort* Vt = Ki + (size_t)B_SZ * NKV * 64;                // 16*32*1024

  k_qkv<<<dim3(B_SZ * 16), dim3(1024), 0, stream>>>(
      x, w_t, b_t, w_p, b_p, w_o, b_o, Qi, Ki, Vt);
  k_attn<<<dim3(B_SZ * 64), dim3(256), 0, stream>>>(
      Qi, Ki, Vt, x, w_W, b_W, z);
}

// Round 7
// 131.305 us; speedup vs baseline: 1.3901x; 1.3901x over previous
//
#include <hip/hip_runtime.h>
#include <math.h>

// Round 7:
// k_qkv: coalesced float4 x loads -> LDS transpose (pixel-major) -> MFMA convs.
//        No channel-strided global reads anywhere.
// k_attn: split-KV: 4 waves share 64 q-rows, each owns a 256-kv quarter
//        (private P buffer, zero main-loop barriers, 4x less K/V L2 traffic);
//        merge accO/accS via LDS adds (no-max softmax sums are additive);
//        MFMA W-conv epilogue + residual.

#define B_SZ 16
#define C_IN 64
#define C_INT 32
#define HW 4096
#define NKV 1024
#define PSTR 72    // P row stride (ushorts): 64 kv + 8 pad
#define YSTR 40    // y row stride (ushorts): 32 ch + 8 pad
#define CSTR 66    // sx row stride (floats): 64 ch + 2 pad (8-way write / ~2-way read banks)
#define LOG2E 1.4426950408889634f

typedef __attribute__((ext_vector_type(8))) short bfrag;
typedef __attribute__((ext_vector_type(4))) float f32x4;

static __device__ __forceinline__ ushort f2bf(float v) {
  union { float f; uint u; } c; c.f = v;
  uint b = c.u + 0x7FFFu + ((c.u >> 16) & 1u);
  return (ushort)(b >> 16);
}
static __device__ __forceinline__ float bf2f(ushort h) {
  union { uint u; float f; } c; c.u = (uint)h << 16; return c.f;
}

// ---------------- kernel 1: Q/K/V via MFMA, coalesced x ----------------
// 512 thr = 8 waves; block = 128 pixels = 2 image rows; grid = 16*32.
// Wave W owns m-tile of 16 pixels. A = x[m=pix][k=ch] from LDS, B = w^T.
__global__ __launch_bounds__(512) void k_qkv(
    const float* __restrict__ x,
    const float* __restrict__ wt, const float* __restrict__ bt,
    const float* __restrict__ wp, const float* __restrict__ bp,
    const float* __restrict__ wo, const float* __restrict__ bo,
    ushort* __restrict__ Qi, ushort* __restrict__ Ki, ushort* __restrict__ Vt) {
  __shared__ float sx[128 * CSTR];              // 33792 B, [pix][ch]
  __shared__ float sPool[2][2][32][33];         // 16896 B, [conv][prow][px][ch]

  int t = threadIdx.x;
  int W = t >> 6, lane = t & 63, l15 = lane & 15, quad = lane >> 4;
  int bb = blockIdx.x >> 5, rg = blockIdx.x & 31;
  int p0 = rg * 128;                            // image rows 2rg, 2rg+1

  // ---- coalesced x load (float4/lane) + LDS transpose to [pix][ch]
  #pragma unroll
  for (int i = 0; i < 4; ++i) {
    int f = i * 512 + t;                        // 2048 float4s = 128pix x 64ch
    int c = f >> 5, u = f & 31;
    float4 v = *(const float4*)(x + ((size_t)bb << 18) + (size_t)c * HW + p0 + 4 * u);
    sx[(4*u+0) * CSTR + c] = v.x;
    sx[(4*u+1) * CSTR + c] = v.y;
    sx[(4*u+2) * CSTR + c] = v.z;
    sx[(4*u+3) * CSTR + c] = v.w;
  }
  __syncthreads();

  // ---- x A-frags (hi/lo, 2 k-halves) from LDS (b64 reads)
  int pix = W * 16 + l15;
  bfrag xh[2], xl[2];
  #pragma unroll
  for (int kh = 0; kh < 2; ++kh) {
    int base = pix * CSTR + kh * 32 + quad * 8;
    #pragma unroll
    for (int j2 = 0; j2 < 4; ++j2) {
      float2 d = *(const float2*)&sx[base + 2 * j2];
      ushort h0 = f2bf(d.x), h1 = f2bf(d.y);
      xh[kh][2*j2]   = (short)h0; xl[kh][2*j2]   = (short)f2bf(d.x - bf2f(h0));
      xh[kh][2*j2+1] = (short)h1; xl[kh][2*j2+1] = (short)f2bf(d.y - bf2f(h1));
    }
  }

  f32x4 acc[2];

  // ---- THETA (x LOG2E), 3-term -> Q interleaved [pix][hi(32)|lo(32)]
  acc[0] = (f32x4){0.f,0.f,0.f,0.f}; acc[1] = (f32x4){0.f,0.f,0.f,0.f};
  #pragma unroll
  for (int kh = 0; kh < 2; ++kh)
    #pragma unroll
    for (int nt = 0; nt < 2; ++nt) {
      bfrag wh, wl;
      const float* wrow = wt + (size_t)(nt * 16 + l15) * 64 + kh * 32 + quad * 8;
      #pragma unroll
      for (int j = 0; j < 8; ++j) {
        float v = wrow[j] * LOG2E;
        ushort hb = f2bf(v);
        wh[j] = (short)hb; wl[j] = (short)f2bf(v - bf2f(hb));
      }
      acc[nt] = __builtin_amdgcn_mfma_f32_16x16x32_bf16(xh[kh], wh, acc[nt], 0, 0, 0);
      acc[nt] = __builtin_amdgcn_mfma_f32_16x16x32_bf16(xl[kh], wh, acc[nt], 0, 0, 0);
      acc[nt] = __builtin_amdgcn_mfma_f32_16x16x32_bf16(xh[kh], wl, acc[nt], 0, 0, 0);
    }
  #pragma unroll
  for (int nt = 0; nt < 2; ++nt) {
    float bias = bt[nt * 16 + l15] * LOG2E;
    ushort* qb = Qi + ((size_t)bb * HW + p0 + W * 16) * 64 + nt * 16 + l15;
    #pragma unroll
    for (int r = 0; r < 4; ++r) {
      float v = acc[nt][r] + bias;
      ushort hb = f2bf(v);
      qb[(size_t)(quad * 4 + r) * 64]      = hb;
      qb[(size_t)(quad * 4 + r) * 64 + 32] = f2bf(v - bf2f(hb));
    }
  }

  int prow = (W * 16 + quad * 4) >> 6;
  int px2  = ((W * 16 + quad * 4) & 63) >> 1;

  // ---- PHI, 3-term -> x-pair max into sPool[0]
  acc[0] = (f32x4){0.f,0.f,0.f,0.f}; acc[1] = (f32x4){0.f,0.f,0.f,0.f};
  #pragma unroll
  for (int kh = 0; kh < 2; ++kh)
    #pragma unroll
    for (int nt = 0; nt < 2; ++nt) {
      bfrag wh, wl;
      const float* wrow = wp + (size_t)(nt * 16 + l15) * 64 + kh * 32 + quad * 8;
      #pragma unroll
      for (int j = 0; j < 8; ++j) {
        float v = wrow[j];
        ushort hb = f2bf(v);
        wh[j] = (short)hb; wl[j] = (short)f2bf(v - bf2f(hb));
      }
      acc[nt] = __builtin_amdgcn_mfma_f32_16x16x32_bf16(xh[kh], wh, acc[nt], 0, 0, 0);
      acc[nt] = __builtin_amdgcn_mfma_f32_16x16x32_bf16(xl[kh], wh, acc[nt], 0, 0, 0);
      acc[nt] = __builtin_amdgcn_mfma_f32_16x16x32_bf16(xh[kh], wl, acc[nt], 0, 0, 0);
    }
  #pragma unroll
  for (int nt = 0; nt < 2; ++nt) {
    float bias = bp[nt * 16 + l15];
    sPool[0][prow][px2    ][nt * 16 + l15] = fmaxf(acc[nt][0], acc[nt][1]) + bias;
    sPool[0][prow][px2 + 1][nt * 16 + l15] = fmaxf(acc[nt][2], acc[nt][3]) + bias;
  }

  // ---- ORIGIN (V), 2-term -> sPool[1]
  acc[0] = (f32x4){0.f,0.f,0.f,0.f}; acc[1] = (f32x4){0.f,0.f,0.f,0.f};
  #pragma unroll
  for (int kh = 0; kh < 2; ++kh)
    #pragma unroll
    for (int nt = 0; nt < 2; ++nt) {
      bfrag wh;
      const float* wrow = wo + (size_t)(nt * 16 + l15) * 64 + kh * 32 + quad * 8;
      #pragma unroll
      for (int j = 0; j < 8; ++j) wh[j] = (short)f2bf(wrow[j]);
      acc[nt] = __builtin_amdgcn_mfma_f32_16x16x32_bf16(xh[kh], wh, acc[nt], 0, 0, 0);
      acc[nt] = __builtin_amdgcn_mfma_f32_16x16x32_bf16(xl[kh], wh, acc[nt], 0, 0, 0);
    }
  #pragma unroll
  for (int nt = 0; nt < 2; ++nt) {
    float bias = bo[nt * 16 + l15];
    sPool[1][prow][px2    ][nt * 16 + l15] = fmaxf(acc[nt][0], acc[nt][1]) + bias;
    sPool[1][prow][px2 + 1][nt * 16 + l15] = fmaxf(acc[nt][2], acc[nt][3]) + bias;
  }
  __syncthreads();

  // ---- row-pair pooling. K: ch-fast lanes (contiguous stores); V: pos-fast.
  for (int f = t; f < 1024; f += 512) {
    int px = f >> 5, ch = f & 31;
    float v = fmaxf(sPool[0][0][px][ch], sPool[0][1][px][ch]);
    ushort hb = f2bf(v);
    size_t idx = ((size_t)bb * NKV + rg * 32 + px) * 64 + ch;
    Ki[idx] = hb;
    Ki[idx + 32] = f2bf(v - bf2f(hb));
  }
  for (int f = t; f < 1024; f += 512) {
    int ch = f >> 5, px = f & 31;
    float v = fmaxf(sPool[1][0][px][ch], sPool[1][1][px][ch]);
    Vt[(size_t)bb * 32 * NKV + (size_t)ch * NKV + rg * 32 + px] = f2bf(v);
  }
}

// ---------------- kernel 2: split-KV MFMA attention + MFMA W-conv ----------------
// 256 thr = 4 waves; block = 64 q-rows; wave w owns kv in [w*256, w*256+256).
__global__ __launch_bounds__(256, 3) void k_attn(
    const ushort* __restrict__ Qi, const ushort* __restrict__ Ki,
    const ushort* __restrict__ Vt,
    const float* __restrict__ x, const float* __restrict__ wW,
    const float* __restrict__ bW, float* __restrict__ z) {
  __shared__ __align__(16) ushort sP[4 * 64 * PSTR];   // 36864 B (P; reused for merge)
  __shared__ __align__(16) ushort sY[2 * 64 * YSTR];   // 10240 B (y hi|lo)

  int t = threadIdx.x;
  int w = t >> 6, lane = t & 63, l15 = lane & 15, quad = lane >> 4;
  int bb = blockIdx.x >> 6;
  int p0 = (blockIdx.x & 63) << 6;

  const ushort* Qb = Qi + ((size_t)bb * HW + p0) * 64;
  const ushort* Kb = Ki + ((size_t)bb * NKV + (size_t)w * 256) * 64;
  const ushort* Vb = Vt + (size_t)bb * 32 * NKV + (size_t)w * 256;
  ushort* myP = sP + w * 64 * PSTR;

  // ---- Q frags (B[k=ch][n=qrow]), 4 m-tiles, hi/lo
  bfrag qh[4], ql[4];
  #pragma unroll
  for (int mt = 0; mt < 4; ++mt) {
    const ushort* qp = Qb + (size_t)(mt * 16 + l15) * 64 + quad * 8;
    qh[mt] = *(const bfrag*)qp;
    ql[mt] = *(const bfrag*)(qp + 32);
  }

  bfrag kh[4], kl[4], vb[2][2];
  auto loadK = [&](int sc) {
    #pragma unroll
    for (int tt = 0; tt < 4; ++tt) {
      const ushort* p = Kb + (size_t)(sc * 64 + tt * 16 + l15) * 64 + quad * 8;
      kh[tt] = *(const bfrag*)p;
      kl[tt] = *(const bfrag*)(p + 32);
    }
  };
  auto loadV = [&](int sc) {
    #pragma unroll
    for (int ks = 0; ks < 2; ++ks)
      #pragma unroll
      for (int nt = 0; nt < 2; ++nt)
        vb[ks][nt] = *(const bfrag*)(Vb + (size_t)(nt * 16 + l15) * NKV
                                        + sc * 64 + ks * 32 + quad * 8);
  };

  f32x4 accO[4][2], accS[4];
  #pragma unroll
  for (int mt = 0; mt < 4; ++mt) {
    accS[mt] = (f32x4){0.f,0.f,0.f,0.f};
    accO[mt][0] = (f32x4){0.f,0.f,0.f,0.f};
    accO[mt][1] = (f32x4){0.f,0.f,0.f,0.f};
  }
  bfrag vones;
  #pragma unroll
  for (int i = 0; i < 8; ++i) vones[i] = (short)0x3F80;

  loadK(0);
  for (int sc = 0; sc < 4; ++sc) {
    loadV(sc);                                   // consumed after S phase
    // ---- S^T = K.Q^T -> exp2 -> P (private buffer, no barrier)
    #pragma unroll
    for (int tt = 0; tt < 4; ++tt)
      #pragma unroll
      for (int mt = 0; mt < 4; ++mt) {
        f32x4 s = (f32x4){0.f,0.f,0.f,0.f};
        s = __builtin_amdgcn_mfma_f32_16x16x32_bf16(kh[tt], qh[mt], s, 0, 0, 0);
        s = __builtin_amdgcn_mfma_f32_16x16x32_bf16(kh[tt], ql[mt], s, 0, 0, 0);
        s = __builtin_amdgcn_mfma_f32_16x16x32_bf16(kl[tt], qh[mt], s, 0, 0, 0);
        float e0 = exp2f(s[0]), e1 = exp2f(s[1]);
        float e2 = exp2f(s[2]), e3 = exp2f(s[3]);
        uint2 pk;
        pk.x = (__float_as_uint(e0) >> 16) | (__float_as_uint(e1) & 0xFFFF0000u);
        pk.y = (__float_as_uint(e2) >> 16) | (__float_as_uint(e3) & 0xFFFF0000u);
        *(uint2*)&myP[(mt * 16 + l15) * PSTR + tt * 16 + quad * 4] = pk;
      }
    if (sc < 3) loadK(sc + 1);                   // K latency hidden under PV
    // ---- O += P.V ; row-sums via ones-MFMA
    #pragma unroll
    for (int ks = 0; ks < 2; ++ks)
      #pragma unroll
      for (int mt = 0; mt < 4; ++mt) {
        bfrag a = *(const bfrag*)&myP[(mt * 16 + l15) * PSTR + ks * 32 + quad * 8];
        accO[mt][0] = __builtin_amdgcn_mfma_f32_16x16x32_bf16(a, vb[ks][0], accO[mt][0], 0, 0, 0);
        accO[mt][1] = __builtin_amdgcn_mfma_f32_16x16x32_bf16(a, vb[ks][1], accO[mt][1], 0, 0, 0);
        accS[mt]    = __builtin_amdgcn_mfma_f32_16x16x32_bf16(a, vones,     accS[mt],    0, 0, 0);
      }
  }

  // ---- merge partial O / sums across the 4 waves (sums are additive)
  __syncthreads();
  float* mrg = (float*)sP;                       // [4][64][33]
  float* sS  = mrg + 4 * 64 * 33;                // [4][64]
  #pragma unroll
  for (int mt = 0; mt < 4; ++mt)
    #pragma unroll
    for (int r = 0; r < 4; ++r) {
      int q = mt * 16 + quad * 4 + r;
      mrg[(w * 64 + q) * 33 + l15]      = accO[mt][0][r];
      mrg[(w * 64 + q) * 33 + 16 + l15] = accO[mt][1][r];
      if (l15 == 0) sS[w * 64 + q] = accS[mt][r];
    }
  __syncthreads();

  // ---- reduce + normalize -> y bf16 hi/lo
  #pragma unroll
  for (int i = 0; i < 8; ++i) {
    int e = i * 256 + t;
    int q = e >> 5, ch = e & 31;
    float v = mrg[q * 33 + ch] + mrg[(64 + q) * 33 + ch]
            + mrg[(128 + q) * 33 + ch] + mrg[(192 + q) * 33 + ch];
    float ssum = sS[q] + sS[64 + q] + sS[128 + q] + sS[192 + q];
    float y = v * __builtin_amdgcn_rcpf(ssum);
    ushort hb = f2bf(y);
    sY[q * YSTR + ch] = hb;
    sY[64 * YSTR + q * YSTR + ch] = f2bf(y - bf2f(hb));
  }
  __syncthreads();

  // ---- z = W.y + bW + x  (MFMA; wave w owns out-ch [w*16, w*16+16))
  bfrag ah, al;
  {
    const float* wrow = wW + (size_t)(w * 16 + l15) * 32 + quad * 8;
    #pragma unroll
    for (int j = 0; j < 8; ++j) {
      float v = wrow[j];
      ushort hb = f2bf(v);
      ah[j] = (short)hb; al[j] = (short)f2bf(v - bf2f(hb));
    }
  }
  float bWr[4];
  #pragma unroll
  for (int r = 0; r < 4; ++r) bWr[r] = bW[w * 16 + quad * 4 + r];
  #pragma unroll
  for (int nt = 0; nt < 4; ++nt) {
    bfrag yh = *(const bfrag*)&sY[(nt * 16 + l15) * YSTR + quad * 8];
    bfrag yl = *(const bfrag*)&sY[64 * YSTR + (nt * 16 + l15) * YSTR + quad * 8];
    f32x4 d = (f32x4){0.f,0.f,0.f,0.f};
    d = __builtin_amdgcn_mfma_f32_16x16x32_bf16(ah, yh, d, 0, 0, 0);
    d = __builtin_amdgcn_mfma_f32_16x16x32_bf16(al, yh, d, 0, 0, 0);
    d = __builtin_amdgcn_mfma_f32_16x16x32_bf16(ah, yl, d, 0, 0, 0);
    #pragma unroll
    for (int r = 0; r < 4; ++r) {
      size_t zi = ((size_t)bb << 18) + ((size_t)(w * 16 + quad * 4 + r) << 12)
                + p0 + nt * 16 + l15;
      z[zi] = d[r] + bWr[r] + x[zi];
    }
  }
}

extern "C" void kernel_launch(void* const* d_in, const int* in_sizes, int n_in,
                              void* d_out, int out_size, void* d_ws, size_t ws_size,
                              hipStream_t stream) {
  const float* x   = (const float*)d_in[0];
  const float* w_o = (const float*)d_in[1];
  const float* b_o = (const float*)d_in[2];
  const float* w_t = (const float*)d_in[3];
  const float* b_t = (const float*)d_in[4];
  const float* w_p = (const float*)d_in[5];
  const float* b_p = (const float*)d_in[6];
  const float* w_W = (const float*)d_in[7];
  const float* b_W = (const float*)d_in[8];
  float* z = (float*)d_out;

  ushort* Qi = (ushort*)d_ws;                               // 16*4096*64
  ushort* Ki = Qi + (size_t)B_SZ * HW * 64;                 // 16*1024*64
  ushort* Vt = Ki + (size_t)B_SZ * NKV * 64;                // 16*32*1024

  k_qkv<<<dim3(B_SZ * 32), dim3(512), 0, stream>>>(
      x, w_t, b_t, w_p, b_p, w_o, b_o, Qi, Ki, Vt);
  k_attn<<<dim3(B_SZ * 64), dim3(256), 0, stream>>>(
      Qi, Ki, Vt, x, w_W, b_W, z);
}

// Round 8
// 128.039 us; speedup vs baseline: 1.4255x; 1.0255x over previous
//
#include <hip/hip_runtime.h>
#include <math.h>

// Round 8: register-chained MFMA attention.
//  - S^T tile (C-layout) == B-operand of K=16 MFMA  =>  P stays in VGPRs
//    (exp2 -> pack -> directly PV via mfma_f32_16x16x16bf16_1k, A = V^T).
//  - Normalized O^T (C-layout) == y B-frag of the K=16 W-conv epilogue.
//  - Q/K/V stored in pre-swizzled frag-order planes (coalesced b128/b64).
//  - split-KV by wave (L2 traffic 786->197 MB); small fp32 merge via LDS.
//  - k_qkv: coalesced float4 x -> LDS transpose (stride 65, conflict-free
//    b32 reads) -> MFMA convs -> swizzled emits. LOG2E folded into theta.

#define B_SZ 16
#define HW 4096
#define NKV 1024
#define XSTR 65
#define YS 40
#define LOG2E 1.4426950408889634f

typedef __attribute__((ext_vector_type(8))) short bfrag;
typedef __attribute__((ext_vector_type(4))) short sfrag;
typedef __attribute__((ext_vector_type(4))) float f32x4;

static __device__ __forceinline__ ushort f2bf(float v) {
  union { float f; uint u; } c; c.f = v;
  uint b = c.u + 0x7FFFu + ((c.u >> 16) & 1u);
  return (ushort)(b >> 16);
}
static __device__ __forceinline__ float bf2f(ushort h) {
  union { uint u; float f; } c; c.u = (uint)h << 16; return c.f;
}

// ---------------- kernel 1: Q/K/V via MFMA -> swizzled frag planes ----------------
// 512 thr = 8 waves; block = 128 pixels = 2 image rows; grid = 16*32.
__global__ __launch_bounds__(512) void k_qkv(
    const float* __restrict__ x,
    const float* __restrict__ wt, const float* __restrict__ bt,
    const float* __restrict__ wp, const float* __restrict__ bp,
    const float* __restrict__ wo, const float* __restrict__ bo,
    ushort* __restrict__ QH, ushort* __restrict__ QL,
    ushort* __restrict__ KH, ushort* __restrict__ KL, ushort* __restrict__ VF) {
  __shared__ float sx[128 * XSTR];              // 33280 B  [pix][ch] (reused for theta)
  __shared__ float sPool[2][2][32][33];         // 16896 B

  int t = threadIdx.x;
  int W = t >> 6, lane = t & 63, l15 = lane & 15, quad = lane >> 4;
  int bb = blockIdx.x >> 5, rg = blockIdx.x & 31;
  int p0 = rg * 128;

  // coalesced x load + transpose to [pix][ch]
  #pragma unroll
  for (int i = 0; i < 4; ++i) {
    int f = i * 512 + t;
    int c = f >> 5, u = f & 31;
    float4 v = *(const float4*)(x + ((size_t)bb << 18) + (size_t)c * HW + p0 + 4 * u);
    sx[(4*u+0) * XSTR + c] = v.x;
    sx[(4*u+1) * XSTR + c] = v.y;
    sx[(4*u+2) * XSTR + c] = v.z;
    sx[(4*u+3) * XSTR + c] = v.w;
  }
  __syncthreads();

  // x A-frags (hi/lo, 2 k-halves) from LDS (b32, conflict-free)
  int pix = W * 16 + l15;
  bfrag xh[2], xl[2];
  #pragma unroll
  for (int kh2 = 0; kh2 < 2; ++kh2)
    #pragma unroll
    for (int j = 0; j < 8; ++j) {
      float v = sx[pix * XSTR + kh2 * 32 + quad * 8 + j];
      ushort hb = f2bf(v);
      xh[kh2][j] = (short)hb;
      xl[kh2][j] = (short)f2bf(v - bf2f(hb));
    }
  __syncthreads();   // frags in regs; sx region now writable

  f32x4 acc[2];

  // THETA (x LOG2E), 3-term -> fp32 back into sx[pix][ch]
  acc[0] = (f32x4){0.f,0.f,0.f,0.f}; acc[1] = (f32x4){0.f,0.f,0.f,0.f};
  #pragma unroll
  for (int kh2 = 0; kh2 < 2; ++kh2)
    #pragma unroll
    for (int nt = 0; nt < 2; ++nt) {
      bfrag wh, wl;
      const float* wrow = wt + (size_t)(nt * 16 + l15) * 64 + kh2 * 32 + quad * 8;
      #pragma unroll
      for (int j = 0; j < 8; ++j) {
        float v = wrow[j] * LOG2E;
        ushort hb = f2bf(v);
        wh[j] = (short)hb; wl[j] = (short)f2bf(v - bf2f(hb));
      }
      acc[nt] = __builtin_amdgcn_mfma_f32_16x16x32_bf16(xh[kh2], wh, acc[nt], 0, 0, 0);
      acc[nt] = __builtin_amdgcn_mfma_f32_16x16x32_bf16(xl[kh2], wh, acc[nt], 0, 0, 0);
      acc[nt] = __builtin_amdgcn_mfma_f32_16x16x32_bf16(xh[kh2], wl, acc[nt], 0, 0, 0);
    }
  #pragma unroll
  for (int nt = 0; nt < 2; ++nt) {
    float bias = bt[nt * 16 + l15] * LOG2E;
    #pragma unroll
    for (int r = 0; r < 4; ++r)
      sx[(W * 16 + quad * 4 + r) * XSTR + nt * 16 + l15] = acc[nt][r] + bias;
  }

  int prow = (W * 16 + quad * 4) >> 6;
  int px2  = ((W * 16 + quad * 4) & 63) >> 1;

  // PHI, 3-term -> horizontal-pair max into sPool[0]
  acc[0] = (f32x4){0.f,0.f,0.f,0.f}; acc[1] = (f32x4){0.f,0.f,0.f,0.f};
  #pragma unroll
  for (int kh2 = 0; kh2 < 2; ++kh2)
    #pragma unroll
    for (int nt = 0; nt < 2; ++nt) {
      bfrag wh, wl;
      const float* wrow = wp + (size_t)(nt * 16 + l15) * 64 + kh2 * 32 + quad * 8;
      #pragma unroll
      for (int j = 0; j < 8; ++j) {
        float v = wrow[j];
        ushort hb = f2bf(v);
        wh[j] = (short)hb; wl[j] = (short)f2bf(v - bf2f(hb));
      }
      acc[nt] = __builtin_amdgcn_mfma_f32_16x16x32_bf16(xh[kh2], wh, acc[nt], 0, 0, 0);
      acc[nt] = __builtin_amdgcn_mfma_f32_16x16x32_bf16(xl[kh2], wh, acc[nt], 0, 0, 0);
      acc[nt] = __builtin_amdgcn_mfma_f32_16x16x32_bf16(xh[kh2], wl, acc[nt], 0, 0, 0);
    }
  #pragma unroll
  for (int nt = 0; nt < 2; ++nt) {
    float bias = bp[nt * 16 + l15];
    sPool[0][prow][px2    ][nt * 16 + l15] = fmaxf(acc[nt][0], acc[nt][1]) + bias;
    sPool[0][prow][px2 + 1][nt * 16 + l15] = fmaxf(acc[nt][2], acc[nt][3]) + bias;
  }

  // ORIGIN (V), 2-term -> sPool[1]
  acc[0] = (f32x4){0.f,0.f,0.f,0.f}; acc[1] = (f32x4){0.f,0.f,0.f,0.f};
  #pragma unroll
  for (int kh2 = 0; kh2 < 2; ++kh2)
    #pragma unroll
    for (int nt = 0; nt < 2; ++nt) {
      bfrag wh;
      const float* wrow = wo + (size_t)(nt * 16 + l15) * 64 + kh2 * 32 + quad * 8;
      #pragma unroll
      for (int j = 0; j < 8; ++j) wh[j] = (short)f2bf(wrow[j]);
      acc[nt] = __builtin_amdgcn_mfma_f32_16x16x32_bf16(xh[kh2], wh, acc[nt], 0, 0, 0);
      acc[nt] = __builtin_amdgcn_mfma_f32_16x16x32_bf16(xl[kh2], wh, acc[nt], 0, 0, 0);
    }
  #pragma unroll
  for (int nt = 0; nt < 2; ++nt) {
    float bias = bo[nt * 16 + l15];
    sPool[1][prow][px2    ][nt * 16 + l15] = fmaxf(acc[nt][0], acc[nt][1]) + bias;
    sPool[1][prow][px2 + 1][nt * 16 + l15] = fmaxf(acc[nt][2], acc[nt][3]) + bias;
  }
  __syncthreads();

  // ---- emit Q frags: QH/QL[((bb*256+gqt)*64+lane)*8 + j] = theta[q=gqt*16+l15][ch=quad*8+j]
  {
    int qt = t >> 6, ln = t & 63, fl = ln & 15, fq = ln >> 4;
    union { ushort u[8]; uint4 v; } Hh, Ll;
    #pragma unroll
    for (int j = 0; j < 8; ++j) {
      float v = sx[(qt * 16 + fl) * XSTR + fq * 8 + j];
      ushort hb = f2bf(v);
      Hh.u[j] = hb;
      Ll.u[j] = f2bf(v - bf2f(hb));
    }
    size_t base = ((size_t)(bb * 256 + rg * 8 + qt) * 64 + ln) * 8;
    *(uint4*)(QH + base) = Hh.v;
    *(uint4*)(QL + base) = Ll.v;
  }

  // ---- emit K frags: KH/KL[((bb*64+gt)*64+lane)*8 + j] = K[kv=gt*16+l15][ch=quad*8+j]
  #pragma unroll
  for (int f = t; f < 1024; f += 512) {
    int tt = f >> 9, rem = f & 511;
    int ln = rem >> 3, j = rem & 7;
    int kvl = tt * 16 + (ln & 15);
    int ch = (ln >> 4) * 8 + j;
    float v = fmaxf(sPool[0][0][kvl][ch], sPool[0][1][kvl][ch]);
    ushort hb = f2bf(v);
    size_t base = ((size_t)(bb * 64 + rg * 2 + tt) * 64 + ln) * 8 + j;
    KH[base] = hb;
    KL[base] = f2bf(v - bf2f(hb));
  }

  // ---- emit V frags: VF[(((bb*64+gt)*2+mt)*64+lane)*4 + j] = V[kv=gt*16+quad*4+j][ch=mt*16+l15]
  #pragma unroll
  for (int f = t; f < 1024; f += 512) {
    int tt = f >> 9, mt = (f >> 8) & 1;
    int ln = (f >> 2) & 63, j = f & 3;
    int kvl = tt * 16 + ((ln >> 4) << 2) + j;
    int ch = mt * 16 + (ln & 15);
    float v = fmaxf(sPool[1][0][kvl][ch], sPool[1][1][kvl][ch]);
    VF[(((size_t)(bb * 64 + rg * 2 + tt) * 2 + mt) * 64 + ln) * 4 + j] = f2bf(v);
  }
}

// ---------------- kernel 2: register-chained flash attention ----------------
// 256 thr = 4 waves; block = 64 q (4 tiles); wave w owns kv [w*256, w*256+256).
__global__ __launch_bounds__(256, 4) void k_attn(
    const ushort* __restrict__ QH, const ushort* __restrict__ QL,
    const ushort* __restrict__ KH, const ushort* __restrict__ KL,
    const ushort* __restrict__ VF,
    const float* __restrict__ x, const float* __restrict__ wW,
    const float* __restrict__ bW, float* __restrict__ z) {
  __shared__ float smem[4 * 64 * 36 + 4 * 64];   // 37888 B: mrgO + sS (mrg reused for y)
  float* mrg = smem;                              // [w][q 64][ch 36]
  float* sS  = smem + 4 * 64 * 36;                // [w][q 64]

  int t = threadIdx.x;
  int w = t >> 6, lane = t & 63, l15 = lane & 15, quad = lane >> 4;
  int bb = blockIdx.x >> 6;
  int bq = blockIdx.x & 63;                       // block q-tile group (4 tiles)

  // Q frags for the block's 4 q-tiles (B[k=ch][n=q]), hi/lo
  bfrag qh[4], ql[4];
  #pragma unroll
  for (int qt = 0; qt < 4; ++qt) {
    size_t base = ((size_t)(bb * 256 + bq * 4 + qt) * 64 + lane) * 8;
    qh[qt] = *(const bfrag*)(QH + base);
    ql[qt] = *(const bfrag*)(QL + base);
  }

  const ushort* KHb = KH + (size_t)bb * 64 * 64 * 8;
  const ushort* KLb = KL + (size_t)bb * 64 * 64 * 8;
  const ushort* VFb = VF + (size_t)bb * 64 * 2 * 64 * 4;

  f32x4 accO[4][2];
  float spart[4] = {0.f, 0.f, 0.f, 0.f};
  #pragma unroll
  for (int qt = 0; qt < 4; ++qt) {
    accO[qt][0] = (f32x4){0.f,0.f,0.f,0.f};
    accO[qt][1] = (f32x4){0.f,0.f,0.f,0.f};
  }

  bfrag kh[2], kl[2];
  sfrag vf[2][2];
  auto loadT = [&](int buf, int i) {
    int gt = w * 16 + i;
    size_t kb = ((size_t)gt * 64 + lane) * 8;
    kh[buf] = *(const bfrag*)(KHb + kb);
    kl[buf] = *(const bfrag*)(KLb + kb);
    vf[buf][0] = *(const sfrag*)(VFb + (((size_t)gt * 2 + 0) * 64 + lane) * 4);
    vf[buf][1] = *(const sfrag*)(VFb + (((size_t)gt * 2 + 1) * 64 + lane) * 4);
  };

  loadT(0, 0);
  #pragma unroll 2
  for (int i = 0; i < 16; ++i) {
    int cur = i & 1;
    if (i < 15) loadT(cur ^ 1, i + 1);
    #pragma unroll
    for (int qt = 0; qt < 4; ++qt) {
      f32x4 s = (f32x4){0.f,0.f,0.f,0.f};
      s = __builtin_amdgcn_mfma_f32_16x16x32_bf16(kh[cur], qh[qt], s, 0, 0, 0);
      s = __builtin_amdgcn_mfma_f32_16x16x32_bf16(kh[cur], ql[qt], s, 0, 0, 0);
      s = __builtin_amdgcn_mfma_f32_16x16x32_bf16(kl[cur], qh[qt], s, 0, 0, 0);
      float e0 = exp2f(s[0]), e1 = exp2f(s[1]);
      float e2 = exp2f(s[2]), e3 = exp2f(s[3]);
      spart[qt] += (e0 + e1) + (e2 + e3);
      union { uint2 u; sfrag s4; } pk;   // truncation: normalization cancels bias
      pk.u.x = (__float_as_uint(e0) >> 16) | (__float_as_uint(e1) & 0xFFFF0000u);
      pk.u.y = (__float_as_uint(e2) >> 16) | (__float_as_uint(e3) & 0xFFFF0000u);
      // P^T C-layout == B-frag of K=16 MFMA; A = V^T  ->  O^T += V^T . P^T
      accO[qt][0] = __builtin_amdgcn_mfma_f32_16x16x16bf16_1k(vf[cur][0], pk.s4, accO[qt][0], 0, 0, 0);
      accO[qt][1] = __builtin_amdgcn_mfma_f32_16x16x16bf16_1k(vf[cur][1], pk.s4, accO[qt][1], 0, 0, 0);
    }
  }

  // wave-level kv-sum: reduce spart across the 4 quads (lanes xor 16/32)
  #pragma unroll
  for (int qt = 0; qt < 4; ++qt) {
    spart[qt] += __shfl_xor(spart[qt], 16);
    spart[qt] += __shfl_xor(spart[qt], 32);
  }

  // merge partials across waves
  #pragma unroll
  for (int qt = 0; qt < 4; ++qt) {
    #pragma unroll
    for (int mt = 0; mt < 2; ++mt)
      *(float4*)&mrg[((size_t)w * 64 + qt * 16 + l15) * 36 + mt * 16 + quad * 4] =
          make_float4(accO[qt][mt][0], accO[qt][mt][1], accO[qt][mt][2], accO[qt][mt][3]);
    if (lane < 16) sS[w * 64 + qt * 16 + l15] = spart[qt];
  }
  __syncthreads();

  // reduce over waves + normalize (thread -> q = t>>2, 8 channels)
  int rq = t >> 2, rc = (t & 3) * 8;
  float yv[8];
  {
    float ssum = sS[rq] + sS[64 + rq] + sS[128 + rq] + sS[192 + rq];
    float inv = 1.0f / ssum;
    #pragma unroll
    for (int h = 0; h < 2; ++h) {
      float4 a = *(const float4*)&mrg[(size_t)rq * 36 + rc + 4 * h];
      float4 b = *(const float4*)&mrg[(size_t)(64 + rq) * 36 + rc + 4 * h];
      float4 c = *(const float4*)&mrg[(size_t)(128 + rq) * 36 + rc + 4 * h];
      float4 d = *(const float4*)&mrg[(size_t)(192 + rq) * 36 + rc + 4 * h];
      yv[4*h+0] = (a.x + b.x + c.x + d.x) * inv;
      yv[4*h+1] = (a.y + b.y + c.y + d.y) * inv;
      yv[4*h+2] = (a.z + b.z + c.z + d.z) * inv;
      yv[4*h+3] = (a.w + b.w + c.w + d.w) * inv;
    }
  }
  __syncthreads();

  // write y bf16 hi/lo planes into reused mrg space
  ushort* yH = (ushort*)mrg;                 // [q][YS]
  ushort* yL = yH + 64 * YS;
  {
    union { ushort u[8]; uint4 v; } Hh, Ll;
    #pragma unroll
    for (int j = 0; j < 8; ++j) {
      ushort hb = f2bf(yv[j]);
      Hh.u[j] = hb;
      Ll.u[j] = f2bf(yv[j] - bf2f(hb));
    }
    *(uint4*)&yH[rq * YS + rc] = Hh.v;
    *(uint4*)&yL[rq * YS + rc] = Ll.v;
  }
  __syncthreads();

  // epilogue: wave w -> cout tile [w*16, w*16+16); z = W.y + bW + x
  #pragma unroll
  for (int nt = 0; nt < 4; ++nt) {
    f32x4 d = (f32x4){0.f,0.f,0.f,0.f};
    #pragma unroll
    for (int kt = 0; kt < 2; ++kt) {
      float4 w4 = *(const float4*)&wW[(size_t)(w * 16 + l15) * 32 + kt * 16 + quad * 4];
      sfrag ah, al, yhf, ylf;
      #pragma unroll
      for (int j = 0; j < 4; ++j) {
        float v = (&w4.x)[j];
        ushort hb = f2bf(v);
        ah[j] = (short)hb; al[j] = (short)f2bf(v - bf2f(hb));
      }
      yhf = *(const sfrag*)&yH[(nt * 16 + l15) * YS + kt * 16 + quad * 4];
      ylf = *(const sfrag*)&yL[(nt * 16 + l15) * YS + kt * 16 + quad * 4];
      d = __builtin_amdgcn_mfma_f32_16x16x16bf16_1k(ah, yhf, d, 0, 0, 0);
      d = __builtin_amdgcn_mfma_f32_16x16x16bf16_1k(al, yhf, d, 0, 0, 0);
      d = __builtin_amdgcn_mfma_f32_16x16x16bf16_1k(ah, ylf, d, 0, 0, 0);
    }
    #pragma unroll
    for (int r = 0; r < 4; ++r) {
      int cout = w * 16 + quad * 4 + r;
      size_t zi = ((size_t)bb << 18) + ((size_t)cout << 12)
                + (size_t)(bq * 4 + nt) * 16 + l15;
      z[zi] = d[r] + bW[cout] + x[zi];
    }
  }
}

extern "C" void kernel_launch(void* const* d_in, const int* in_sizes, int n_in,
                              void* d_out, int out_size, void* d_ws, size_t ws_size,
                              hipStream_t stream) {
  const float* x   = (const float*)d_in[0];
  const float* w_o = (const float*)d_in[1];
  const float* b_o = (const float*)d_in[2];
  const float* w_t = (const float*)d_in[3];
  const float* b_t = (const float*)d_in[4];
  const float* w_p = (const float*)d_in[5];
  const float* b_p = (const float*)d_in[6];
  const float* w_W = (const float*)d_in[7];
  const float* b_W = (const float*)d_in[8];
  float* z = (float*)d_out;

  ushort* QH = (ushort*)d_ws;                         // 16*256*64*8 = 2097152
  ushort* QL = QH + 2097152;
  ushort* KH = QL + 2097152;                          // 16*64*64*8 = 524288
  ushort* KL = KH + 524288;
  ushort* VF = KL + 524288;                           // 16*64*2*64*4 = 524288

  k_qkv<<<dim3(B_SZ * 32), dim3(512), 0, stream>>>(
      x, w_t, b_t, w_p, b_p, w_o, b_o, QH, QL, KH, KL, VF);
  k_attn<<<dim3(B_SZ * 64), dim3(256), 0, stream>>>(
      QH, QL, KH, KL, VF, x, w_W, b_W, z);
}